// Round 1
// baseline (62.754 us; speedup 1.0000x reference)
//
#include <hip/hip_runtime.h>

// YOLO loss: preds/targets (N,7,7,2*(5+20)) fp32 -> scalar fp32.
// S=7, B=2, C=20, LAMBDA_NOOBJ=0.5, EPS=1e-9, divide by N at the end.

#define NPC 50          // floats per cell per tensor = B*(5+C)
#define CPB 128         // cells per block
#define TPB 128         // threads per block (= CPB, thread-per-cell)
#define CCLS 20

__device__ __forceinline__ float iou_xywh(float px, float py, float pw, float ph,
                                          float tx, float ty, float tw, float th) {
    float ax1 = px - pw * 0.5f, ay1 = py - ph * 0.5f;
    float ax2 = px + pw * 0.5f, ay2 = py + ph * 0.5f;
    float bx1 = tx - tw * 0.5f, by1 = ty - th * 0.5f;
    float bx2 = tx + tw * 0.5f, by2 = ty + th * 0.5f;
    float iw = fmaxf(fminf(ax2, bx2) - fmaxf(ax1, bx1), 0.0f);
    float ih = fmaxf(fminf(ay2, by2) - fmaxf(ay1, by1), 0.0f);
    float inter = iw * ih;
    float uni = pw * ph + tw * th - inter;
    return inter / (uni + 1e-9f);
}

__global__ __launch_bounds__(TPB) void yolo_loss_kernel(
        const float* __restrict__ preds,
        const float* __restrict__ targets,
        float* __restrict__ out,
        int ncells, float invN) {
    __shared__ float lp[CPB * NPC];   // 25.6 KB
    __shared__ float lt[CPB * NPC];   // 25.6 KB
    __shared__ float wsum[TPB / 64];

    const int tid = threadIdx.x;
    const long long cell0 = (long long)blockIdx.x * CPB;
    const long long base = cell0 * NPC;                 // float offset of tile
    const int cells_here = min(CPB, ncells - (int)cell0);
    const int f4_count = cells_here * NPC / 4;          // cells_here*50 may not /4 on tail
    const int f_total = cells_here * NPC;

    // ---- coalesced float4 staging (tile base is 16B-aligned: CPB*NPC*4 = 25600B) ----
    const float4* gp = (const float4*)(preds + base);
    const float4* gt = (const float4*)(targets + base);
    float4* sp = (float4*)lp;
    float4* st = (float4*)lt;
    for (int i = tid; i < f4_count; i += TPB) {
        sp[i] = gp[i];
        st[i] = gt[i];
    }
    // tail floats (only possible in a ragged last block; full blocks: 1600 float4 exactly)
    for (int i = f4_count * 4 + tid; i < f_total; i += TPB) {
        lp[i] = preds[base + i];
        lt[i] = targets[base + i];
    }
    __syncthreads();

    float cell = 0.0f;
    if ((int)cell0 + tid < ncells) {
        const float* cp = lp + tid * NPC;
        const float* ct = lt + tid * NPC;

        // boxes: b=0 at [0..4], b=1 at [25..29]
        float iou0 = iou_xywh(cp[0], cp[1], cp[2], cp[3],
                              ct[0], ct[1], ct[2], ct[3]);
        float iou1 = iou_xywh(cp[25], cp[26], cp[27], cp[28],
                              ct[25], ct[26], ct[27], ct[28]);
        int best = (iou1 > iou0) ? 1 : 0;   // argmax, first-max tie-break
        bool has_obj = (ct[4] > 0.0f) || (ct[29] > 0.0f);

        float dx, dy;
        if (best == 0) { dx = cp[0] - ct[0];   dy = cp[1] - ct[1]; }
        else           { dx = cp[25] - ct[25]; dy = cp[26] - ct[26]; }
        float dxy = dx * dx + dy * dy;
        cell = has_obj ? dxy : 0.0f;

        // classes of b = B-1 = 1: channels [30..49]
        float csum = 0.0f;
        float bv = ct[30];   // running max of tc (strict > keeps first max)
        float pg = cp[30];   // pc at argmax(tc)
        #pragma unroll
        for (int k = 0; k < CCLS; ++k) {
            float tv = ct[30 + k];
            float pv = cp[30 + k];
            float d = pv - tv;
            csum += d * d;
            if (k > 0 && tv > bv) { bv = tv; pg = pv; }
        }
        cell += csum;

        // conf term: (iou_b * p_gt - iou_b)^2, weight 1 at best else 0.5
        float f = pg - 1.0f;
        float f2 = f * f;
        float e0 = iou0 * iou0 * f2;
        float e1 = iou1 * iou1 * f2;
        cell += (best == 0) ? e0 : 0.5f * e0;
        cell += (best == 1) ? e1 : 0.5f * e1;
    }

    // ---- block reduction: wave64 shuffle -> LDS partials -> one atomic ----
    float v = cell;
    #pragma unroll
    for (int off = 32; off >= 1; off >>= 1) v += __shfl_down(v, off);
    const int wid = tid >> 6;
    const int lane = tid & 63;
    if (lane == 0) wsum[wid] = v;
    __syncthreads();
    if (tid == 0) {
        float s = 0.0f;
        #pragma unroll
        for (int w = 0; w < TPB / 64; ++w) s += wsum[w];
        atomicAdd(out, s * invN);
    }
}

extern "C" void kernel_launch(void* const* d_in, const int* in_sizes, int n_in,
                              void* d_out, int out_size, void* d_ws, size_t ws_size,
                              hipStream_t stream) {
    const float* preds = (const float*)d_in[0];
    const float* targets = (const float*)d_in[1];
    float* out = (float*)d_out;

    const int ncells = in_sizes[0] / NPC;          // N*S*S = 401408
    const int N = ncells / 49;                      // S*S = 49
    const int nblk = (ncells + CPB - 1) / CPB;      // 3136 (exact)

    hipMemsetAsync(out, 0, sizeof(float), stream);
    yolo_loss_kernel<<<nblk, TPB, 0, stream>>>(preds, targets, out,
                                               ncells, 1.0f / (float)N);
}

// Round 2
// 58.976 us; speedup vs baseline: 1.0641x; 1.0641x over previous
//
#include <hip/hip_runtime.h>

// YOLO loss: preds/targets (N,7,7,2*(5+20)) fp32 -> scalar fp32.
// S=7, B=2, C=20, LAMBDA_NOOBJ=0.5, EPS=1e-9, divide by N at the end.
//
// R1: staging via __builtin_amdgcn_global_load_lds (16B/lane, direct to LDS,
// no VGPR round trip) -- 25 x 1KB chunks per wave issued back-to-back, one
// vmcnt drain at the barrier. Wave0 stages preds tile, wave1 targets tile.

#define NPC 50          // floats per cell per tensor = B*(5+C)
#define CPB 128         // cells per block
#define TPB 128         // threads per block (= CPB, thread-per-cell)

typedef const __attribute__((address_space(1))) void gvoid_t;
typedef __attribute__((address_space(3))) void lvoid_t;

__device__ __forceinline__ float iou_xywh(float px, float py, float pw, float ph,
                                          float tx, float ty, float tw, float th) {
    float ax1 = px - pw * 0.5f, ay1 = py - ph * 0.5f;
    float ax2 = px + pw * 0.5f, ay2 = py + ph * 0.5f;
    float bx1 = tx - tw * 0.5f, by1 = ty - th * 0.5f;
    float bx2 = tx + tw * 0.5f, by2 = ty + th * 0.5f;
    float iw = fmaxf(fminf(ax2, bx2) - fmaxf(ax1, bx1), 0.0f);
    float ih = fmaxf(fminf(ay2, by2) - fmaxf(ay1, by1), 0.0f);
    float inter = iw * ih;
    float uni = pw * ph + tw * th - inter;
    return inter / (uni + 1e-9f);
}

__global__ __launch_bounds__(TPB) void yolo_loss_kernel(
        const float* __restrict__ preds,
        const float* __restrict__ targets,
        float* __restrict__ out,
        int ncells, float invN) {
    __shared__ float lp[CPB * NPC];   // 25.6 KB
    __shared__ float lt[CPB * NPC];   // 25.6 KB
    __shared__ float wsum[TPB / 64];

    const int tid = threadIdx.x;
    const int wave = tid >> 6;
    const int lane = tid & 63;
    const long long cell0 = (long long)blockIdx.x * CPB;
    const long long base = cell0 * NPC;                 // float offset of tile
    const int cells_here = min(CPB, ncells - (int)cell0);

    if (cells_here == CPB) {
        // ---- fast path: 25 x 1KB global->LDS direct per wave ----
        // wave0: preds tile, wave1: targets tile. Linear LDS layout (identity
        // mapping: lane*16B), exactly what global_load_lds requires.
        const float* src = (wave == 0) ? (preds + base) : (targets + base);
        float* dst = (wave == 0) ? lp : lt;
        #pragma unroll
        for (int c = 0; c < 25; ++c) {
            __builtin_amdgcn_global_load_lds(
                (gvoid_t*)(src + c * 256 + lane * 4),
                (lvoid_t*)(dst + c * 256),
                16, 0, 0);
        }
        asm volatile("s_waitcnt vmcnt(0)" ::: "memory");
    } else {
        // ---- ragged tail fallback (not hit for N*S*S % 128 == 0) ----
        const int f_total = cells_here * NPC;
        for (int i = tid; i < f_total; i += TPB) {
            lp[i] = preds[base + i];
            lt[i] = targets[base + i];
        }
    }
    __syncthreads();

    float cell = 0.0f;
    if ((int)cell0 + tid < ncells) {
        // cell base = tid*200B: 8B aligned -> float2 reads
        const float2* cp2 = (const float2*)(lp + tid * NPC);
        const float2* ct2 = (const float2*)(lt + tid * NPC);

        float2 p01 = cp2[0];            // p0,p1
        float2 p23 = cp2[1];            // p2,p3
        float2 t01 = ct2[0];
        float2 t23 = ct2[1];
        float2 t4_ = ct2[2];            // t4, t5(unused)
        float2 pA = cp2[12];            // p24(unused), p25
        float2 pB = cp2[13];            // p26, p27
        float2 pC = cp2[14];            // p28, p29(unused)
        float2 tA = ct2[12];
        float2 tB = ct2[13];
        float2 tC = ct2[14];

        float iou0 = iou_xywh(p01.x, p01.y, p23.x, p23.y,
                              t01.x, t01.y, t23.x, t23.y);
        float iou1 = iou_xywh(pA.y, pB.x, pB.y, pC.x,
                              tA.y, tB.x, tB.y, tC.x);
        int best = (iou1 > iou0) ? 1 : 0;   // argmax, first-max tie-break
        bool has_obj = (t4_.x > 0.0f) || (tC.y > 0.0f);

        float dx, dy;
        if (best == 0) { dx = p01.x - t01.x; dy = p01.y - t01.y; }
        else           { dx = pA.y - tA.y;   dy = pB.x - tB.x;   }
        float dxy = dx * dx + dy * dy;
        cell = has_obj ? dxy : 0.0f;

        // classes of b = B-1 = 1: channels [30..49] = float2 idx [15..24]
        float csum = 0.0f;
        float bv = -1e30f;   // running max of tc (strict > keeps first max)
        float pg = 0.0f;     // pc at argmax(tc)
        #pragma unroll
        for (int j = 0; j < 10; ++j) {
            float2 tv = ct2[15 + j];
            float2 pv = cp2[15 + j];
            float d0 = pv.x - tv.x;
            float d1 = pv.y - tv.y;
            csum += d0 * d0 + d1 * d1;
            if (tv.x > bv) { bv = tv.x; pg = pv.x; }
            if (tv.y > bv) { bv = tv.y; pg = pv.y; }
        }
        cell += csum;

        // conf term: (iou_b * p_gt - iou_b)^2, weight 1 at best else 0.5
        float f = pg - 1.0f;
        float f2 = f * f;
        float e0 = iou0 * iou0 * f2;
        float e1 = iou1 * iou1 * f2;
        cell += (best == 0) ? e0 : 0.5f * e0;
        cell += (best == 1) ? e1 : 0.5f * e1;
    }

    // ---- block reduction: wave64 shuffle -> LDS partials -> one atomic ----
    float v = cell;
    #pragma unroll
    for (int off = 32; off >= 1; off >>= 1) v += __shfl_down(v, off);
    if (lane == 0) wsum[wave] = v;
    __syncthreads();
    if (tid == 0) {
        float s = 0.0f;
        #pragma unroll
        for (int w = 0; w < TPB / 64; ++w) s += wsum[w];
        atomicAdd(out, s * invN);
    }
}

extern "C" void kernel_launch(void* const* d_in, const int* in_sizes, int n_in,
                              void* d_out, int out_size, void* d_ws, size_t ws_size,
                              hipStream_t stream) {
    const float* preds = (const float*)d_in[0];
    const float* targets = (const float*)d_in[1];
    float* out = (float*)d_out;

    const int ncells = in_sizes[0] / NPC;          // N*S*S = 401408
    const int N = ncells / 49;                      // S*S = 49
    const int nblk = (ncells + CPB - 1) / CPB;      // 3136 (exact)

    hipMemsetAsync(out, 0, sizeof(float), stream);
    yolo_loss_kernel<<<nblk, TPB, 0, stream>>>(preds, targets, out,
                                               ncells, 1.0f / (float)N);
}

// Round 3
// 33.784 us; speedup vs baseline: 1.8575x; 1.7457x over previous
//
#include <hip/hip_runtime.h>

// YOLO loss: preds/targets (N,7,7,2*(5+20)) fp32 -> scalar fp32.
// S=7, B=2, C=20, LAMBDA_NOOBJ=0.5, EPS=1e-9, divide by N at the end.
//
// R3: kill the same-address atomicAdd chain (3136 serialized memory-side
// RMWs ~= 55us, the real R0-R2 limiter; evidence: WRITE_SIZE = 3136*32B).
// Blocks store partials to d_ws (distinct addresses, parallel), tiny second
// kernel reduces 3136 floats -> scalar. Staging stays global_load_lds (R2).

#define NPC 50          // floats per cell per tensor = B*(5+C)
#define CPB 128         // cells per block
#define TPB 128         // threads per block (= CPB, thread-per-cell)

typedef const __attribute__((address_space(1))) void gvoid_t;
typedef __attribute__((address_space(3))) void lvoid_t;

__device__ __forceinline__ float iou_xywh(float px, float py, float pw, float ph,
                                          float tx, float ty, float tw, float th) {
    float ax1 = px - pw * 0.5f, ay1 = py - ph * 0.5f;
    float ax2 = px + pw * 0.5f, ay2 = py + ph * 0.5f;
    float bx1 = tx - tw * 0.5f, by1 = ty - th * 0.5f;
    float bx2 = tx + tw * 0.5f, by2 = ty + th * 0.5f;
    float iw = fmaxf(fminf(ax2, bx2) - fmaxf(ax1, bx1), 0.0f);
    float ih = fmaxf(fminf(ay2, by2) - fmaxf(ay1, by1), 0.0f);
    float inter = iw * ih;
    float uni = pw * ph + tw * th - inter;
    return inter / (uni + 1e-9f);
}

__global__ __launch_bounds__(TPB) void yolo_partial_kernel(
        const float* __restrict__ preds,
        const float* __restrict__ targets,
        float* __restrict__ part,
        int ncells) {
    __shared__ float lp[CPB * NPC];   // 25.6 KB
    __shared__ float lt[CPB * NPC];   // 25.6 KB
    __shared__ float wsum[TPB / 64];

    const int tid = threadIdx.x;
    const int wave = tid >> 6;
    const int lane = tid & 63;
    const long long cell0 = (long long)blockIdx.x * CPB;
    const long long base = cell0 * NPC;                 // float offset of tile
    const int cells_here = min(CPB, ncells - (int)cell0);

    if (cells_here == CPB) {
        // ---- fast path: 25 x 1KB global->LDS direct per wave ----
        const float* src = (wave == 0) ? (preds + base) : (targets + base);
        float* dst = (wave == 0) ? lp : lt;
        #pragma unroll
        for (int c = 0; c < 25; ++c) {
            __builtin_amdgcn_global_load_lds(
                (gvoid_t*)(src + c * 256 + lane * 4),
                (lvoid_t*)(dst + c * 256),
                16, 0, 0);
        }
        asm volatile("s_waitcnt vmcnt(0)" ::: "memory");
    } else {
        // ---- ragged tail fallback (not hit: N*S*S % 128 == 0) ----
        const int f_total = cells_here * NPC;
        for (int i = tid; i < f_total; i += TPB) {
            lp[i] = preds[base + i];
            lt[i] = targets[base + i];
        }
    }
    __syncthreads();

    float cell = 0.0f;
    if ((int)cell0 + tid < ncells) {
        // cell base = tid*200B: 8B aligned -> float2 reads
        const float2* cp2 = (const float2*)(lp + tid * NPC);
        const float2* ct2 = (const float2*)(lt + tid * NPC);

        float2 p01 = cp2[0];            // p0,p1
        float2 p23 = cp2[1];            // p2,p3
        float2 t01 = ct2[0];
        float2 t23 = ct2[1];
        float2 t4_ = ct2[2];            // t4, t5(unused)
        float2 pA = cp2[12];            // p24(unused), p25
        float2 pB = cp2[13];            // p26, p27
        float2 pC = cp2[14];            // p28, p29(unused)
        float2 tA = ct2[12];
        float2 tB = ct2[13];
        float2 tC = ct2[14];

        float iou0 = iou_xywh(p01.x, p01.y, p23.x, p23.y,
                              t01.x, t01.y, t23.x, t23.y);
        float iou1 = iou_xywh(pA.y, pB.x, pB.y, pC.x,
                              tA.y, tB.x, tB.y, tC.x);
        int best = (iou1 > iou0) ? 1 : 0;   // argmax, first-max tie-break
        bool has_obj = (t4_.x > 0.0f) || (tC.y > 0.0f);

        float dx, dy;
        if (best == 0) { dx = p01.x - t01.x; dy = p01.y - t01.y; }
        else           { dx = pA.y - tA.y;   dy = pB.x - tB.x;   }
        float dxy = dx * dx + dy * dy;
        cell = has_obj ? dxy : 0.0f;

        // classes of b = B-1 = 1: channels [30..49] = float2 idx [15..24]
        float csum = 0.0f;
        float bv = -1e30f;   // running max of tc (strict > keeps first max)
        float pg = 0.0f;     // pc at argmax(tc)
        #pragma unroll
        for (int j = 0; j < 10; ++j) {
            float2 tv = ct2[15 + j];
            float2 pv = cp2[15 + j];
            float d0 = pv.x - tv.x;
            float d1 = pv.y - tv.y;
            csum += d0 * d0 + d1 * d1;
            if (tv.x > bv) { bv = tv.x; pg = pv.x; }
            if (tv.y > bv) { bv = tv.y; pg = pv.y; }
        }
        cell += csum;

        // conf term: (iou_b * p_gt - iou_b)^2, weight 1 at best else 0.5
        float f = pg - 1.0f;
        float f2 = f * f;
        float e0 = iou0 * iou0 * f2;
        float e1 = iou1 * iou1 * f2;
        cell += (best == 0) ? e0 : 0.5f * e0;
        cell += (best == 1) ? e1 : 0.5f * e1;
    }

    // ---- block reduction: wave64 shuffle -> LDS partials -> one store ----
    float v = cell;
    #pragma unroll
    for (int off = 32; off >= 1; off >>= 1) v += __shfl_down(v, off);
    if (lane == 0) wsum[wave] = v;
    __syncthreads();
    if (tid == 0) {
        float s = 0.0f;
        #pragma unroll
        for (int w = 0; w < TPB / 64; ++w) s += wsum[w];
        part[blockIdx.x] = s;           // distinct address per block: no chain
    }
}

__global__ __launch_bounds__(256) void yolo_final_kernel(
        const float* __restrict__ part, float* __restrict__ out,
        int nblk, float invN) {
    __shared__ float wsum[4];
    const int tid = threadIdx.x;
    float s = 0.0f;
    for (int i = tid; i < nblk; i += 256) s += part[i];
    #pragma unroll
    for (int off = 32; off >= 1; off >>= 1) s += __shfl_down(s, off);
    if ((tid & 63) == 0) wsum[tid >> 6] = s;
    __syncthreads();
    if (tid == 0) {
        out[0] = (wsum[0] + wsum[1] + wsum[2] + wsum[3]) * invN;
    }
}

extern "C" void kernel_launch(void* const* d_in, const int* in_sizes, int n_in,
                              void* d_out, int out_size, void* d_ws, size_t ws_size,
                              hipStream_t stream) {
    const float* preds = (const float*)d_in[0];
    const float* targets = (const float*)d_in[1];
    float* out = (float*)d_out;
    float* part = (float*)d_ws;                     // nblk floats of scratch

    const int ncells = in_sizes[0] / NPC;          // N*S*S = 401408
    const int N = ncells / 49;                      // S*S = 49
    const int nblk = (ncells + CPB - 1) / CPB;      // 3136 (exact)

    yolo_partial_kernel<<<nblk, TPB, 0, stream>>>(preds, targets, part, ncells);
    yolo_final_kernel<<<1, 256, 0, stream>>>(part, out, nblk, 1.0f / (float)N);
}